// Round 10
// baseline (212.486 us; speedup 1.0000x reference)
//
#include <hip/hip_runtime.h>

typedef __attribute__((ext_vector_type(8))) short bf16x8;
typedef __attribute__((ext_vector_type(4))) float f32x4;
typedef unsigned int u32;

__device__ __forceinline__ unsigned short f2bf(float f) {
  union { float f; unsigned int u; } a; a.f = f;
  unsigned int u = a.u;
  u += 0x7FFFu + ((u >> 16) & 1u);   // RNE
  return (unsigned short)(u >> 16);
}

// async global->LDS, 16B per lane. LDS dest = wave-uniform base + lane*16.
__device__ __forceinline__ void gload16(const unsigned short* g, unsigned short* l) {
  __builtin_amdgcn_global_load_lds((const __attribute__((address_space(1))) u32*)g,
                                   (__attribute__((address_space(3))) u32*)l, 16, 0, 0);
}

#define BK 64
// Ledger: R13 coarse pipeline REGRESSED. R15 128^2 scores/PV REGRESSED. R16
// scores2w NULL pre-swizzle. R18 8-phase TV NULL (44 vs 43). R19 prep_mt
// REGRESSED. R20 XCD swizzle WIN 217->204 (scores/PV gained; TV's over-fetch
// was L3-absorbed). R21 scores2wz+mt64 net -2.5 BUT gemm_tv8 blew up 44->68.5
// with byte-identical source: rule-#19 co-compile perturbation broke the
// fragile 8-phase asm schedule (MfmaUtil 29->19.5). The 8-phase TV was null
// when healthy and fragile under codegen drift -> REPLACED.
// R22: TV back on the robust 2-barrier 128x128 structure (42.9us verified at
// session baseline) as standalone gemm_tv2 + XCD swizzle. All other kernels
// byte-identical to the R21 build (scores2wz/mt64/PV just won; don't touch).

// ---------------- baseline 2-barrier GEMM (mode 3 = PV) ----------------
// C = A[M][K] * B[N][K]^T, bf16 in, fp32 accum. 128x64 tile, 4 waves.
// MODE 3: PV, stripe pairs p: seg0 = stripe 15-p (K=128*(16-p)), seg1 =
//         stripe p (K=128*(p+1)); out = C / rsum[row];
//         XCD swizzle over flat = x + 16*y + 128*z (512 blocks)
template<int MODE>
__global__ __launch_bounds__(256, 4)
void gemm_bt(const unsigned short* __restrict__ A,
             const unsigned short* __restrict__ Bm,
             float* __restrict__ Cf,
             float* __restrict__ Cf2,
             unsigned short* __restrict__ Cb,
             int K, long aBatch, long bBatch, long cBatch, float scale)
{
  constexpr int NI    = 2;
  constexpr int BROWS = 16;
  constexpr int BG    = 2;

  int z, bm0 = 0, bn, p = 0;
  if (MODE == 3) {
    int flat = blockIdx.x + 16 * blockIdx.y + 128 * blockIdx.z;  // 512 total
    int rm   = (flat & 7) * 64 + (flat >> 3);      // bijective
    z  = rm >> 7;
    p  = (rm >> 4) & 7;
    bn = (rm & 15) * 64;
  } else {
    z   = blockIdx.z;
    bm0 = blockIdx.y * 128;
    bn  = blockIdx.x * 64;
  }

  A  += (long)z * aBatch;
  Bm += (long)z * bBatch;
  if (MODE == 3) { Cf += (long)z * cBatch; Cf2 += (long)z * 2048; }

  __shared__ __align__(16) unsigned short As[128 * BK];
  __shared__ __align__(16) unsigned short Bs[64 * BK];

  int tid  = threadIdx.x;
  int wave = tid >> 6, lane = tid & 63;
  int wm = wave * 32;
  int quad = lane >> 4, l16 = lane & 15;

  // staging lane coords: 8-row groups, chunk XOR-swizzled (row%8-invariant)
  int r8 = lane >> 3;
  int c  = (lane & 7) ^ r8;
  const unsigned short* Bg = Bm + (long)(bn + wave * BROWS + r8) * K + c * 8;
  unsigned short* Al = &As[(wave * 32) * BK];
  unsigned short* Bl = &Bs[(wave * BROWS) * BK];

  const int nseg = (MODE == 3) ? 2 : 1;
  for (int seg = 0; seg < nseg; seg++) {
    int bm   = (MODE == 3) ? ((seg == 0) ? (15 - p) * 128 : p * 128) : bm0;
    int Keff = (MODE == 3) ? ((seg == 0) ? 128 * (16 - p) : 128 * (p + 1)) : K;
    const unsigned short* Ag = A + (long)(bm + wave * 32 + r8) * K + c * 8;

    f32x4 acc[NI][4] = {};

    for (int k0 = 0; k0 < Keff; k0 += BK) {
#pragma unroll
      for (int g = 0; g < 4; g++)
        gload16(Ag + k0 + (long)g * 8 * K, Al + g * 8 * BK);
#pragma unroll
      for (int g = 0; g < BG; g++)
        gload16(Bg + k0 + (long)g * 8 * K, Bl + g * 8 * BK);
      __syncthreads();

#pragma unroll
      for (int h = 0; h < 2; h++) {
        bf16x8 af[NI], bfr[4];
#pragma unroll
        for (int i = 0; i < NI; i++)
          af[i]  = *(const bf16x8*)&As[(wm + i * 16 + l16) * BK + (((quad + 4 * h) ^ (l16 & 7)) * 8)];
#pragma unroll
        for (int j = 0; j < 4; j++)
          bfr[j] = *(const bf16x8*)&Bs[(j * 16 + l16) * BK + (((quad + 4 * h) ^ (l16 & 7)) * 8)];
#pragma unroll
        for (int i = 0; i < NI; i++)
#pragma unroll
          for (int j = 0; j < 4; j++)
            acc[i][j] = __builtin_amdgcn_mfma_f32_16x16x32_bf16(af[i], bfr[j], acc[i][j], 0, 0, 0);
      }
      __syncthreads();
    }

    // Epilogue. C/D layout: col = lane&15, row = quad*4 + reg  [m89/m91]
#pragma unroll
    for (int i = 0; i < NI; i++) {
      int grow0 = bm + wm + i * 16 + quad * 4;
      if (MODE == 3) {
        float rinv[4];
#pragma unroll
        for (int r = 0; r < 4; r++) rinv[r] = 1.0f / Cf2[grow0 + r];
#pragma unroll
        for (int j = 0; j < 4; j++) {
          int gcol = bn + j * 16 + l16;
#pragma unroll
          for (int r = 0; r < 4; r++)
            Cf[(long)(grow0 + r) * 1024 + gcol] = acc[i][j][r] * rinv[r];
        }
      } else {
#pragma unroll
        for (int j = 0; j < 4; j++) {
          int gcol = bn + j * 16 + l16;
#pragma unroll
          for (int r = 0; r < 4; r++)
            Cb[(long)(grow0 + r) * 1024 + gcol] = f2bf(acc[i][j][r]);
        }
      }
    }
  }
}

// ---------------- Mt on 64x64 tiles, full-GPU grid (R21) ----------------
// Mt[j][i] = sum_o Wkb[j][o] Wqb[i][o]. 256 blocks (16x16), 256 thr, 4 waves
// each owning 16m x 64n. LDS 16KB. Same XOR-chunk swizzle as gemm_bt.
__global__ __launch_bounds__(256, 4)
void mt64(const unsigned short* __restrict__ Wkb,
          const unsigned short* __restrict__ Wqb,
          unsigned short* __restrict__ Mt)
{
  int bm = blockIdx.y * 64, bn = blockIdx.x * 64;
  __shared__ __align__(16) unsigned short As[64 * 64];
  __shared__ __align__(16) unsigned short Bs[64 * 64];

  int tid  = threadIdx.x;
  int wave = tid >> 6, lane = tid & 63;
  int quad = lane >> 4, l16 = lane & 15;
  int r8 = lane >> 3;
  int c  = (lane & 7) ^ r8;
  const unsigned short* Ag = Wkb + (long)(bm + wave * 16 + r8) * 1024 + c * 8;
  const unsigned short* Bg = Wqb + (long)(bn + wave * 16 + r8) * 1024 + c * 8;
  unsigned short* Al = &As[(wave * 16) * 64];
  unsigned short* Bl = &Bs[(wave * 16) * 64];

  f32x4 acc[4] = {};

  for (int k0 = 0; k0 < 1024; k0 += 64) {
#pragma unroll
    for (int g = 0; g < 2; g++)
      gload16(Ag + k0 + (long)g * 8 * 1024, Al + g * 8 * 64);
#pragma unroll
    for (int g = 0; g < 2; g++)
      gload16(Bg + k0 + (long)g * 8 * 1024, Bl + g * 8 * 64);
    __syncthreads();

#pragma unroll
    for (int h = 0; h < 2; h++) {
      bf16x8 af, bfr[4];
      af = *(const bf16x8*)&As[(wave * 16 + l16) * 64 + (((quad + 4 * h) ^ (l16 & 7)) * 8)];
#pragma unroll
      for (int j = 0; j < 4; j++)
        bfr[j] = *(const bf16x8*)&Bs[(j * 16 + l16) * 64 + (((quad + 4 * h) ^ (l16 & 7)) * 8)];
#pragma unroll
      for (int j = 0; j < 4; j++)
        acc[j] = __builtin_amdgcn_mfma_f32_16x16x32_bf16(af, bfr[j], acc[j], 0, 0, 0);
    }
    __syncthreads();
  }

  int grow0 = bm + wave * 16 + quad * 4;
#pragma unroll
  for (int j = 0; j < 4; j++) {
    int gcol = bn + j * 16 + l16;
#pragma unroll
    for (int r = 0; r < 4; r++)
      Mt[(long)(grow0 + r) * 1024 + gcol] = f2bf(acc[j][r]);
  }
}

// ---------------- scores, 2-wave blocks + XCD swizzle (R21 WIN) ----------
// Per-wave 64x64 output (MFMA-bound geometry: 32 MFMA vs 12 ds_read per
// K-step), block tile 128x64, 1088-block tri grid, LDS 24KB.
__global__ __launch_bounds__(128, 3)
void scores2wz(const unsigned short* __restrict__ T,   // [b][2048][1024]
               const unsigned short* __restrict__ Xb,  // [b][2048][1024]
               float* __restrict__ rsum,               // [b][2048]
               unsigned short* __restrict__ E,         // [b][2048][2048]
               float scale)
{
  // XCD swizzle then triangular decode over 128x64 tiles (272/batch)
  int flat = blockIdx.x + 272 * blockIdx.z;        // 1088 total
  int rm   = (flat & 7) * 136 + (flat >> 3);       // bijective
  int z = rm / 272;
  int f = rm % 272;
  int r = (int)((sqrtf((float)(4 * f + 1)) - 1.0f) * 0.5f);
  while ((r + 1) * (r + 2) <= f) r++;
  while (r * (r + 1) > f) r--;
  int bm0 = r * 128;
  int bn  = (f - r * (r + 1)) * 64;

  const unsigned short* A = T  + (long)z * 2048 * 1024;
  const unsigned short* B = Xb + (long)z * 2048 * 1024;
  unsigned short* Cb = E + (long)z * 2048 * 2048;
  float* Cf = rsum + (long)z * 2048;

  __shared__ __align__(16) unsigned short As[128 * BK];  // 16 KB
  __shared__ __align__(16) unsigned short Bs[64 * BK];   //  8 KB

  int tid  = threadIdx.x;
  int wave = tid >> 6, lane = tid & 63;
  int quad = lane >> 4, l16 = lane & 15;
  int wm   = wave * 64;                 // wave owns 64 rows x all 64 cols

  // staging lane coords: 8-row groups, chunk XOR-swizzled (row%8-invariant)
  int r8 = lane >> 3;
  int c  = (lane & 7) ^ r8;
  const unsigned short* Ag = A + (long)(bm0 + wave * 64 + r8) * 1024 + c * 8;
  const unsigned short* Bg = B + (long)(bn  + wave * 32 + r8) * 1024 + c * 8;
  unsigned short* Al = &As[(wave * 64) * BK];
  unsigned short* Bl = &Bs[(wave * 32) * BK];

  f32x4 acc[4][4] = {};

  for (int k0 = 0; k0 < 1024; k0 += BK) {
#pragma unroll
    for (int g = 0; g < 8; g++)        // A: 64 rows per wave
      gload16(Ag + k0 + (long)g * 8 * 1024, Al + g * 8 * BK);
#pragma unroll
    for (int g = 0; g < 4; g++)        // B: 32 rows per wave
      gload16(Bg + k0 + (long)g * 8 * 1024, Bl + g * 8 * BK);
    __syncthreads();

#pragma unroll
    for (int h = 0; h < 2; h++) {
      bf16x8 af[4], bfr[4];
#pragma unroll
      for (int i = 0; i < 4; i++)
        af[i]  = *(const bf16x8*)&As[(wm + i * 16 + l16) * BK + (((quad + 4 * h) ^ (l16 & 7)) * 8)];
#pragma unroll
      for (int j = 0; j < 4; j++)
        bfr[j] = *(const bf16x8*)&Bs[(j * 16 + l16) * BK + (((quad + 4 * h) ^ (l16 & 7)) * 8)];
#pragma unroll
      for (int i = 0; i < 4; i++)
#pragma unroll
        for (int j = 0; j < 4; j++)
          acc[i][j] = __builtin_amdgcn_mfma_f32_16x16x32_bf16(af[i], bfr[j], acc[i][j], 0, 0, 0);
    }
    __syncthreads();
  }

  // Epilogue: E = exp(C*scale) masked col<=row + row-sum atomics
#pragma unroll
  for (int i = 0; i < 4; i++) {
    int grow0 = bm0 + wm + i * 16 + quad * 4;
#pragma unroll
    for (int rr = 0; rr < 4; rr++) {
      int grow = grow0 + rr;
      float rowpart = 0.f;
#pragma unroll
      for (int j = 0; j < 4; j++) {
        int gcol = bn + j * 16 + l16;
        float e = (gcol <= grow) ? __expf(acc[i][j][rr] * scale) : 0.f;
        rowpart += e;
        Cb[(long)grow * 2048 + gcol] = f2bf(e);
      }
      rowpart += __shfl_xor(rowpart, 1);
      rowpart += __shfl_xor(rowpart, 2);
      rowpart += __shfl_xor(rowpart, 4);
      rowpart += __shfl_xor(rowpart, 8);
      if (l16 == 0) atomicAdd(&Cf[grow], rowpart);
    }
  }
}

// ---------------- R22: fused TV, robust 2-barrier 128x128 + XCD swizzle ----
// The session-baseline MODE-0 structure (verified 42.9us): 256 thr, 4 waves
// (2x2), per-wave 64x64, NI=4, LDS 32KB, 4 blocks/CU. XCD swizzle: 1024
// blocks, chunk of 128 per XCD = 8 m-panels x all 16 n-blocks -> A-panel
// (256KB) L2-resident per 16 consecutive blocks.
__global__ __launch_bounds__(256, 4)
void gemm_tv2(const unsigned short* __restrict__ A,   // Xb [8192][1024]
              const unsigned short* __restrict__ Bm,  // TVB [2048][1024]
              unsigned short* __restrict__ Cb)        // T ; Vt
{
  int flat = blockIdx.x + 16 * blockIdx.y;   // 1024 blocks
  int rm   = (flat & 7) * 128 + (flat >> 3); // bijective
  int bm0 = (rm >> 4) * 128;
  int bn  = (rm & 15) * 128;

  __shared__ __align__(16) unsigned short As[128 * BK];
  __shared__ __align__(16) unsigned short Bs[128 * BK];

  int tid  = threadIdx.x;
  int wave = tid >> 6, lane = tid & 63;
  int wm = (wave >> 1) * 64;
  int wn = (wave & 1) * 64;
  int quad = lane >> 4, l16 = lane & 15;

  // staging lane coords: 8-row groups, chunk XOR-swizzled (row%8-invariant)
  int r8 = lane >> 3;
  int c  = (lane & 7) ^ r8;
  const unsigned short* Ag = A  + (long)(bm0 + wave * 32 + r8) * 1024 + c * 8;
  const unsigned short* Bg = Bm + (long)(bn  + wave * 32 + r8) * 1024 + c * 8;
  unsigned short* Al = &As[(wave * 32) * BK];
  unsigned short* Bl = &Bs[(wave * 32) * BK];

  f32x4 acc[4][4] = {};

  for (int k0 = 0; k0 < 1024; k0 += BK) {
#pragma unroll
    for (int g = 0; g < 4; g++)
      gload16(Ag + k0 + (long)g * 8 * 1024, Al + g * 8 * BK);
#pragma unroll
    for (int g = 0; g < 4; g++)
      gload16(Bg + k0 + (long)g * 8 * 1024, Bl + g * 8 * BK);
    __syncthreads();

#pragma unroll
    for (int h = 0; h < 2; h++) {
      bf16x8 af[4], bfr[4];
#pragma unroll
      for (int i = 0; i < 4; i++)
        af[i]  = *(const bf16x8*)&As[(wm + i * 16 + l16) * BK + (((quad + 4 * h) ^ (l16 & 7)) * 8)];
#pragma unroll
      for (int j = 0; j < 4; j++)
        bfr[j] = *(const bf16x8*)&Bs[(wn + j * 16 + l16) * BK + (((quad + 4 * h) ^ (l16 & 7)) * 8)];
#pragma unroll
      for (int i = 0; i < 4; i++)
#pragma unroll
        for (int j = 0; j < 4; j++)
          acc[i][j] = __builtin_amdgcn_mfma_f32_16x16x32_bf16(af[i], bfr[j], acc[i][j], 0, 0, 0);
    }
    __syncthreads();
  }

  // TV split epilogue. C/D layout: col = lane&15, row = quad*4 + reg
#pragma unroll
  for (int i = 0; i < 4; i++) {
    int grow0 = bm0 + wm + i * 16 + quad * 4;
#pragma unroll
    for (int j = 0; j < 4; j++) {
      int gcol = bn + wn + j * 16 + l16;
      int which = gcol >> 10;           // wave-uniform (bn,wn multiples of 64)
      int col = gcol & 1023;
      if (which == 0) {                 // T bf16 row-major [8192][1024]
#pragma unroll
        for (int r = 0; r < 4; r++)
          Cb[(long)(grow0 + r) * 1024 + col] = f2bf(acc[i][j][r]);
      } else {                          // Vt[b][col][s], 4-row pack along s
        unsigned short* Vt = Cb + (long)8192 * 1024;
        int bb = grow0 >> 11, s = grow0 & 2047;
        ushort4 pk;
        pk.x = f2bf(acc[i][j][0]); pk.y = f2bf(acc[i][j][1]);
        pk.z = f2bf(acc[i][j][2]); pk.w = f2bf(acc[i][j][3]);
        *(ushort4*)(Vt + ((long)bb * 1024 + col) * 2048 + s) = pk;
      }
    }
  }
}

// fused prep: [0,8192) x->bf16; [8192,9216) Wq->bf16 (NO transpose);
// [9216,10240) Wk->bf16 (NO transpose); [10240,11264) Wv transpose-convert;
// [11264,11272) zero rsum
__global__ __launch_bounds__(256)
void prep(const float* __restrict__ x,
          const float* __restrict__ W0, const float* __restrict__ W1,
          const float* __restrict__ W2,
          unsigned short* __restrict__ Xb,
          unsigned short* __restrict__ Wqb, unsigned short* __restrict__ Wkb,
          unsigned short* __restrict__ WvT,
          float* __restrict__ rsum)
{
  __shared__ float tile[32][33];
  int b = blockIdx.x;
  if (b < 8192) {
    long i = ((long)b * 256 + threadIdx.x) * 4;
    float4 v = *(const float4*)(x + i);
    ushort4 o;
    o.x = f2bf(v.x); o.y = f2bf(v.y); o.z = f2bf(v.z); o.w = f2bf(v.w);
    *(ushort4*)(Xb + i) = o;
  } else if (b < 10240) {
    int t = b - 8192;
    const float* W    = (t < 1024) ? W0 : W1;
    unsigned short* D = (t < 1024) ? Wqb : Wkb;
    long i = ((long)(t & 1023) * 256 + threadIdx.x) * 4;
    float4 v = *(const float4*)(W + i);
    ushort4 o;
    o.x = f2bf(v.x); o.y = f2bf(v.y); o.z = f2bf(v.z); o.w = f2bf(v.w);
    *(ushort4*)(D + i) = o;
  } else if (b < 11264) {
    int q = b - 10240;
    int kb = (q >> 5) * 32, nb = (q & 31) * 32;
    int tx = threadIdx.x & 31, ty = threadIdx.x >> 5;
    for (int r = ty; r < 32; r += 8)
      tile[r][tx] = W2[(long)(kb + r) * 1024 + nb + tx];
    __syncthreads();
    for (int r = ty; r < 32; r += 8)
      WvT[(long)(nb + r) * 1024 + kb + tx] = f2bf(tile[tx][r]);
  } else {
    long i = ((long)(b - 11264) * 256 + threadIdx.x) * 4;
    float4 zz = {0.f, 0.f, 0.f, 0.f};
    *(float4*)(rsum + i) = zz;
  }
}

extern "C" void kernel_launch(void* const* d_in, const int* in_sizes, int n_in,
                              void* d_out, int out_size, void* d_ws, size_t ws_size,
                              hipStream_t stream) {
  const float* x  = (const float*)d_in[0];
  const float* Wq = (const float*)d_in[1];
  const float* Wk = (const float*)d_in[2];
  const float* Wv = (const float*)d_in[3];
  float* out = (float*)d_out;

  // workspace layout (bf16 = unsigned short), ~120 MB
  unsigned short* Xb  = (unsigned short*)d_ws;            // [8192][1024]
  unsigned short* Wqb = Xb  + (long)8192 * 1024;          // [1024][1024] bf16 [in][out]
  unsigned short* Wkb = Wqb + (long)1024 * 1024;          // [1024][1024] bf16 [in][out]
  unsigned short* TVB = Wkb + (long)1024 * 1024;          // [2048][1024]: Mt ; WvT
  unsigned short* T   = TVB + (long)2048 * 1024;          // [8192][1024]
  unsigned short* Vt  = T   + (long)8192 * 1024;          // [4][1024][2048] (follows T!)
  unsigned short* E   = Vt  + (long)8192 * 1024;          // [4][2048][2048] bf16 exp(s)
  float* rsum         = (float*)(E + (long)4 * 2048 * 2048); // [4][2048] fp32

  prep<<<11272, 256, 0, stream>>>(x, Wq, Wk, Wv, Xb, Wqb, Wkb,
                                  TVB + (long)1024 * 1024, rsum);

  // Mt[j][i] = sum_o Wk[j][o] Wq[i][o] = M[i][j], M = Wq Wk^T (full-GPU grid)
  mt64<<<dim3(16, 16, 1), 256, 0, stream>>>(Wkb, Wqb, TVB);

  // fused TV: [8192x2048] = Xb * [Mt;WvT]^T; robust 2-barrier + XCD swizzle
  gemm_tv2<<<dim3(16, 64, 1), 256, 0, stream>>>(Xb, TVB, T);

  // E = exp(T * Xb^T / 32) masked lower-tri + row sums; 2-wave + XCD swizzle
  scores2wz<<<dim3(272, 1, 4), 128, 0, stream>>>(T, Xb, rsum, E, 0.03125f);

  // out = (E * Vt^T)/rsum; stripe pairs (15-p, p) + XCD swizzle
  gemm_bt<3><<<dim3(16, 8, 4), 256, 0, stream>>>(E, Vt, out, rsum, nullptr, 2048,
      (long)2048 * 2048, (long)1024 * 2048, (long)2048 * 1024, 1.f);
}

// Round 11
// 203.266 us; speedup vs baseline: 1.0454x; 1.0454x over previous
//
#include <hip/hip_runtime.h>

typedef __attribute__((ext_vector_type(8))) short bf16x8;
typedef __attribute__((ext_vector_type(4))) float f32x4;
typedef unsigned int u32;

__device__ __forceinline__ unsigned short f2bf(float f) {
  union { float f; unsigned int u; } a; a.f = f;
  unsigned int u = a.u;
  u += 0x7FFFu + ((u >> 16) & 1u);   // RNE
  return (unsigned short)(u >> 16);
}

// async global->LDS, 16B per lane. LDS dest = wave-uniform base + lane*16.
__device__ __forceinline__ void gload16(const unsigned short* g, unsigned short* l) {
  __builtin_amdgcn_global_load_lds((const __attribute__((address_space(1))) u32*)g,
                                   (__attribute__((address_space(3))) u32*)l, 16, 0, 0);
}

#define BK 64
// Ledger: R13 coarse pipeline REGRESSED. R15 128^2 scores/PV REGRESSED. R16
// scores2w NULL pre-swizzle. R18 8-phase TV NULL. R19 prep_mt REGRESSED.
// R20 XCD swizzle on scores/PV WIN 217->204 (TV's FETCH drop was free: L3).
// R21 scores2wz+mt64: total 201.9 (best) but tv8 blew 44->68.5 (rule-#19
// sibling codegen drift on fragile asm schedule). R22 swizzled tv2: TV 48.4
// (worse than 42.9 unswizzled; WRITE inflated 33->53MB) and others +30.7 on
// byte-identical source -> total 212.5. Lesson: swizzle TV = useless-to-bad
// (reads L3-absorbed, writes inflate); keep swizzle ONLY on scores/PV.
// R23: single diff vs R22 - gemm_tv2 UNSWIZZLED (R0-verified 42.9us
// indexing). A/B: if "others" recover to R21 levels, TV-swizzle was
// implicated; else it's compile-lottery and R24 reverts to literal R21.

// ---------------- baseline 2-barrier GEMM (mode 3 = PV) ----------------
// C = A[M][K] * B[N][K]^T, bf16 in, fp32 accum. 128x64 tile, 4 waves.
// MODE 3: PV, stripe pairs p: seg0 = stripe 15-p (K=128*(16-p)), seg1 =
//         stripe p (K=128*(p+1)); out = C / rsum[row];
//         XCD swizzle over flat = x + 16*y + 128*z (512 blocks)
template<int MODE>
__global__ __launch_bounds__(256, 4)
void gemm_bt(const unsigned short* __restrict__ A,
             const unsigned short* __restrict__ Bm,
             float* __restrict__ Cf,
             float* __restrict__ Cf2,
             unsigned short* __restrict__ Cb,
             int K, long aBatch, long bBatch, long cBatch, float scale)
{
  constexpr int NI    = 2;
  constexpr int BROWS = 16;
  constexpr int BG    = 2;

  int z, bm0 = 0, bn, p = 0;
  if (MODE == 3) {
    int flat = blockIdx.x + 16 * blockIdx.y + 128 * blockIdx.z;  // 512 total
    int rm   = (flat & 7) * 64 + (flat >> 3);      // bijective
    z  = rm >> 7;
    p  = (rm >> 4) & 7;
    bn = (rm & 15) * 64;
  } else {
    z   = blockIdx.z;
    bm0 = blockIdx.y * 128;
    bn  = blockIdx.x * 64;
  }

  A  += (long)z * aBatch;
  Bm += (long)z * bBatch;
  if (MODE == 3) { Cf += (long)z * cBatch; Cf2 += (long)z * 2048; }

  __shared__ __align__(16) unsigned short As[128 * BK];
  __shared__ __align__(16) unsigned short Bs[64 * BK];

  int tid  = threadIdx.x;
  int wave = tid >> 6, lane = tid & 63;
  int wm = wave * 32;
  int quad = lane >> 4, l16 = lane & 15;

  // staging lane coords: 8-row groups, chunk XOR-swizzled (row%8-invariant)
  int r8 = lane >> 3;
  int c  = (lane & 7) ^ r8;
  const unsigned short* Bg = Bm + (long)(bn + wave * BROWS + r8) * K + c * 8;
  unsigned short* Al = &As[(wave * 32) * BK];
  unsigned short* Bl = &Bs[(wave * BROWS) * BK];

  const int nseg = (MODE == 3) ? 2 : 1;
  for (int seg = 0; seg < nseg; seg++) {
    int bm   = (MODE == 3) ? ((seg == 0) ? (15 - p) * 128 : p * 128) : bm0;
    int Keff = (MODE == 3) ? ((seg == 0) ? 128 * (16 - p) : 128 * (p + 1)) : K;
    const unsigned short* Ag = A + (long)(bm + wave * 32 + r8) * K + c * 8;

    f32x4 acc[NI][4] = {};

    for (int k0 = 0; k0 < Keff; k0 += BK) {
#pragma unroll
      for (int g = 0; g < 4; g++)
        gload16(Ag + k0 + (long)g * 8 * K, Al + g * 8 * BK);
#pragma unroll
      for (int g = 0; g < BG; g++)
        gload16(Bg + k0 + (long)g * 8 * K, Bl + g * 8 * BK);
      __syncthreads();

#pragma unroll
      for (int h = 0; h < 2; h++) {
        bf16x8 af[NI], bfr[4];
#pragma unroll
        for (int i = 0; i < NI; i++)
          af[i]  = *(const bf16x8*)&As[(wm + i * 16 + l16) * BK + (((quad + 4 * h) ^ (l16 & 7)) * 8)];
#pragma unroll
        for (int j = 0; j < 4; j++)
          bfr[j] = *(const bf16x8*)&Bs[(j * 16 + l16) * BK + (((quad + 4 * h) ^ (l16 & 7)) * 8)];
#pragma unroll
        for (int i = 0; i < NI; i++)
#pragma unroll
          for (int j = 0; j < 4; j++)
            acc[i][j] = __builtin_amdgcn_mfma_f32_16x16x32_bf16(af[i], bfr[j], acc[i][j], 0, 0, 0);
      }
      __syncthreads();
    }

    // Epilogue. C/D layout: col = lane&15, row = quad*4 + reg  [m89/m91]
#pragma unroll
    for (int i = 0; i < NI; i++) {
      int grow0 = bm + wm + i * 16 + quad * 4;
      if (MODE == 3) {
        float rinv[4];
#pragma unroll
        for (int r = 0; r < 4; r++) rinv[r] = 1.0f / Cf2[grow0 + r];
#pragma unroll
        for (int j = 0; j < 4; j++) {
          int gcol = bn + j * 16 + l16;
#pragma unroll
          for (int r = 0; r < 4; r++)
            Cf[(long)(grow0 + r) * 1024 + gcol] = acc[i][j][r] * rinv[r];
        }
      } else {
#pragma unroll
        for (int j = 0; j < 4; j++) {
          int gcol = bn + j * 16 + l16;
#pragma unroll
          for (int r = 0; r < 4; r++)
            Cb[(long)(grow0 + r) * 1024 + gcol] = f2bf(acc[i][j][r]);
        }
      }
    }
  }
}

// ---------------- Mt on 64x64 tiles, full-GPU grid (R21) ----------------
// Mt[j][i] = sum_o Wkb[j][o] Wqb[i][o]. 256 blocks (16x16), 256 thr, 4 waves
// each owning 16m x 64n. LDS 16KB. Same XOR-chunk swizzle as gemm_bt.
__global__ __launch_bounds__(256, 4)
void mt64(const unsigned short* __restrict__ Wkb,
          const unsigned short* __restrict__ Wqb,
          unsigned short* __restrict__ Mt)
{
  int bm = blockIdx.y * 64, bn = blockIdx.x * 64;
  __shared__ __align__(16) unsigned short As[64 * 64];
  __shared__ __align__(16) unsigned short Bs[64 * 64];

  int tid  = threadIdx.x;
  int wave = tid >> 6, lane = tid & 63;
  int quad = lane >> 4, l16 = lane & 15;
  int r8 = lane >> 3;
  int c  = (lane & 7) ^ r8;
  const unsigned short* Ag = Wkb + (long)(bm + wave * 16 + r8) * 1024 + c * 8;
  const unsigned short* Bg = Wqb + (long)(bn + wave * 16 + r8) * 1024 + c * 8;
  unsigned short* Al = &As[(wave * 16) * 64];
  unsigned short* Bl = &Bs[(wave * 16) * 64];

  f32x4 acc[4] = {};

  for (int k0 = 0; k0 < 1024; k0 += 64) {
#pragma unroll
    for (int g = 0; g < 2; g++)
      gload16(Ag + k0 + (long)g * 8 * 1024, Al + g * 8 * 64);
#pragma unroll
    for (int g = 0; g < 2; g++)
      gload16(Bg + k0 + (long)g * 8 * 1024, Bl + g * 8 * 64);
    __syncthreads();

#pragma unroll
    for (int h = 0; h < 2; h++) {
      bf16x8 af, bfr[4];
      af = *(const bf16x8*)&As[(wave * 16 + l16) * 64 + (((quad + 4 * h) ^ (l16 & 7)) * 8)];
#pragma unroll
      for (int j = 0; j < 4; j++)
        bfr[j] = *(const bf16x8*)&Bs[(j * 16 + l16) * 64 + (((quad + 4 * h) ^ (l16 & 7)) * 8)];
#pragma unroll
      for (int j = 0; j < 4; j++)
        acc[j] = __builtin_amdgcn_mfma_f32_16x16x32_bf16(af, bfr[j], acc[j], 0, 0, 0);
    }
    __syncthreads();
  }

  int grow0 = bm + wave * 16 + quad * 4;
#pragma unroll
  for (int j = 0; j < 4; j++) {
    int gcol = bn + j * 16 + l16;
#pragma unroll
    for (int r = 0; r < 4; r++)
      Mt[(long)(grow0 + r) * 1024 + gcol] = f2bf(acc[j][r]);
  }
}

// ---------------- scores, 2-wave blocks + XCD swizzle (R21 WIN) ----------
// Per-wave 64x64 output (MFMA-bound geometry: 32 MFMA vs 12 ds_read per
// K-step), block tile 128x64, 1088-block tri grid, LDS 24KB.
__global__ __launch_bounds__(128, 3)
void scores2wz(const unsigned short* __restrict__ T,   // [b][2048][1024]
               const unsigned short* __restrict__ Xb,  // [b][2048][1024]
               float* __restrict__ rsum,               // [b][2048]
               unsigned short* __restrict__ E,         // [b][2048][2048]
               float scale)
{
  // XCD swizzle then triangular decode over 128x64 tiles (272/batch)
  int flat = blockIdx.x + 272 * blockIdx.z;        // 1088 total
  int rm   = (flat & 7) * 136 + (flat >> 3);       // bijective
  int z = rm / 272;
  int f = rm % 272;
  int r = (int)((sqrtf((float)(4 * f + 1)) - 1.0f) * 0.5f);
  while ((r + 1) * (r + 2) <= f) r++;
  while (r * (r + 1) > f) r--;
  int bm0 = r * 128;
  int bn  = (f - r * (r + 1)) * 64;

  const unsigned short* A = T  + (long)z * 2048 * 1024;
  const unsigned short* B = Xb + (long)z * 2048 * 1024;
  unsigned short* Cb = E + (long)z * 2048 * 2048;
  float* Cf = rsum + (long)z * 2048;

  __shared__ __align__(16) unsigned short As[128 * BK];  // 16 KB
  __shared__ __align__(16) unsigned short Bs[64 * BK];   //  8 KB

  int tid  = threadIdx.x;
  int wave = tid >> 6, lane = tid & 63;
  int quad = lane >> 4, l16 = lane & 15;
  int wm   = wave * 64;                 // wave owns 64 rows x all 64 cols

  // staging lane coords: 8-row groups, chunk XOR-swizzled (row%8-invariant)
  int r8 = lane >> 3;
  int c  = (lane & 7) ^ r8;
  const unsigned short* Ag = A + (long)(bm0 + wave * 64 + r8) * 1024 + c * 8;
  const unsigned short* Bg = B + (long)(bn  + wave * 32 + r8) * 1024 + c * 8;
  unsigned short* Al = &As[(wave * 64) * BK];
  unsigned short* Bl = &Bs[(wave * 32) * BK];

  f32x4 acc[4][4] = {};

  for (int k0 = 0; k0 < 1024; k0 += BK) {
#pragma unroll
    for (int g = 0; g < 8; g++)        // A: 64 rows per wave
      gload16(Ag + k0 + (long)g * 8 * 1024, Al + g * 8 * BK);
#pragma unroll
    for (int g = 0; g < 4; g++)        // B: 32 rows per wave
      gload16(Bg + k0 + (long)g * 8 * 1024, Bl + g * 8 * BK);
    __syncthreads();

#pragma unroll
    for (int h = 0; h < 2; h++) {
      bf16x8 af[4], bfr[4];
#pragma unroll
      for (int i = 0; i < 4; i++)
        af[i]  = *(const bf16x8*)&As[(wm + i * 16 + l16) * BK + (((quad + 4 * h) ^ (l16 & 7)) * 8)];
#pragma unroll
      for (int j = 0; j < 4; j++)
        bfr[j] = *(const bf16x8*)&Bs[(j * 16 + l16) * BK + (((quad + 4 * h) ^ (l16 & 7)) * 8)];
#pragma unroll
      for (int i = 0; i < 4; i++)
#pragma unroll
        for (int j = 0; j < 4; j++)
          acc[i][j] = __builtin_amdgcn_mfma_f32_16x16x32_bf16(af[i], bfr[j], acc[i][j], 0, 0, 0);
    }
    __syncthreads();
  }

  // Epilogue: E = exp(C*scale) masked col<=row + row-sum atomics
#pragma unroll
  for (int i = 0; i < 4; i++) {
    int grow0 = bm0 + wm + i * 16 + quad * 4;
#pragma unroll
    for (int rr = 0; rr < 4; rr++) {
      int grow = grow0 + rr;
      float rowpart = 0.f;
#pragma unroll
      for (int j = 0; j < 4; j++) {
        int gcol = bn + j * 16 + l16;
        float e = (gcol <= grow) ? __expf(acc[i][j][rr] * scale) : 0.f;
        rowpart += e;
        Cb[(long)grow * 2048 + gcol] = f2bf(e);
      }
      rowpart += __shfl_xor(rowpart, 1);
      rowpart += __shfl_xor(rowpart, 2);
      rowpart += __shfl_xor(rowpart, 4);
      rowpart += __shfl_xor(rowpart, 8);
      if (l16 == 0) atomicAdd(&Cf[grow], rowpart);
    }
  }
}

// ---------------- R23: fused TV, 2-barrier 128x128, UNSWIZZLED ----------
// The session-baseline MODE-0 structure (verified 42.9us): 256 thr, 4 waves
// (2x2), per-wave 64x64, NI=4, LDS 32KB, 4 blocks/CU. No XCD swizzle: TV's
// reads are L3-absorbed (R20: FETCH 67->25MB with zero duration change) and
// swizzle inflated WRITE_SIZE 33->53MB (R22).
__global__ __launch_bounds__(256, 4)
void gemm_tv2(const unsigned short* __restrict__ A,   // Xb [8192][1024]
              const unsigned short* __restrict__ Bm,  // TVB [2048][1024]
              unsigned short* __restrict__ Cb)        // T ; Vt
{
  int bm0 = blockIdx.y * 128;
  int bn  = blockIdx.x * 128;

  __shared__ __align__(16) unsigned short As[128 * BK];
  __shared__ __align__(16) unsigned short Bs[128 * BK];

  int tid  = threadIdx.x;
  int wave = tid >> 6, lane = tid & 63;
  int wm = (wave >> 1) * 64;
  int wn = (wave & 1) * 64;
  int quad = lane >> 4, l16 = lane & 15;

  // staging lane coords: 8-row groups, chunk XOR-swizzled (row%8-invariant)
  int r8 = lane >> 3;
  int c  = (lane & 7) ^ r8;
  const unsigned short* Ag = A  + (long)(bm0 + wave * 32 + r8) * 1024 + c * 8;
  const unsigned short* Bg = Bm + (long)(bn  + wave * 32 + r8) * 1024 + c * 8;
  unsigned short* Al = &As[(wave * 32) * BK];
  unsigned short* Bl = &Bs[(wave * 32) * BK];

  f32x4 acc[4][4] = {};

  for (int k0 = 0; k0 < 1024; k0 += BK) {
#pragma unroll
    for (int g = 0; g < 4; g++)
      gload16(Ag + k0 + (long)g * 8 * 1024, Al + g * 8 * BK);
#pragma unroll
    for (int g = 0; g < 4; g++)
      gload16(Bg + k0 + (long)g * 8 * 1024, Bl + g * 8 * BK);
    __syncthreads();

#pragma unroll
    for (int h = 0; h < 2; h++) {
      bf16x8 af[4], bfr[4];
#pragma unroll
      for (int i = 0; i < 4; i++)
        af[i]  = *(const bf16x8*)&As[(wm + i * 16 + l16) * BK + (((quad + 4 * h) ^ (l16 & 7)) * 8)];
#pragma unroll
      for (int j = 0; j < 4; j++)
        bfr[j] = *(const bf16x8*)&Bs[(wn + j * 16 + l16) * BK + (((quad + 4 * h) ^ (l16 & 7)) * 8)];
#pragma unroll
      for (int i = 0; i < 4; i++)
#pragma unroll
        for (int j = 0; j < 4; j++)
          acc[i][j] = __builtin_amdgcn_mfma_f32_16x16x32_bf16(af[i], bfr[j], acc[i][j], 0, 0, 0);
    }
    __syncthreads();
  }

  // TV split epilogue. C/D layout: col = lane&15, row = quad*4 + reg
#pragma unroll
  for (int i = 0; i < 4; i++) {
    int grow0 = bm0 + wm + i * 16 + quad * 4;
#pragma unroll
    for (int j = 0; j < 4; j++) {
      int gcol = bn + wn + j * 16 + l16;
      int which = gcol >> 10;           // wave-uniform (bn,wn multiples of 64)
      int col = gcol & 1023;
      if (which == 0) {                 // T bf16 row-major [8192][1024]
#pragma unroll
        for (int r = 0; r < 4; r++)
          Cb[(long)(grow0 + r) * 1024 + col] = f2bf(acc[i][j][r]);
      } else {                          // Vt[b][col][s], 4-row pack along s
        unsigned short* Vt = Cb + (long)8192 * 1024;
        int bb = grow0 >> 11, s = grow0 & 2047;
        ushort4 pk;
        pk.x = f2bf(acc[i][j][0]); pk.y = f2bf(acc[i][j][1]);
        pk.z = f2bf(acc[i][j][2]); pk.w = f2bf(acc[i][j][3]);
        *(ushort4*)(Vt + ((long)bb * 1024 + col) * 2048 + s) = pk;
      }
    }
  }
}

// fused prep: [0,8192) x->bf16; [8192,9216) Wq->bf16 (NO transpose);
// [9216,10240) Wk->bf16 (NO transpose); [10240,11264) Wv transpose-convert;
// [11264,11272) zero rsum
__global__ __launch_bounds__(256)
void prep(const float* __restrict__ x,
          const float* __restrict__ W0, const float* __restrict__ W1,
          const float* __restrict__ W2,
          unsigned short* __restrict__ Xb,
          unsigned short* __restrict__ Wqb, unsigned short* __restrict__ Wkb,
          unsigned short* __restrict__ WvT,
          float* __restrict__ rsum)
{
  __shared__ float tile[32][33];
  int b = blockIdx.x;
  if (b < 8192) {
    long i = ((long)b * 256 + threadIdx.x) * 4;
    float4 v = *(const float4*)(x + i);
    ushort4 o;
    o.x = f2bf(v.x); o.y = f2bf(v.y); o.z = f2bf(v.z); o.w = f2bf(v.w);
    *(ushort4*)(Xb + i) = o;
  } else if (b < 10240) {
    int t = b - 8192;
    const float* W    = (t < 1024) ? W0 : W1;
    unsigned short* D = (t < 1024) ? Wqb : Wkb;
    long i = ((long)(t & 1023) * 256 + threadIdx.x) * 4;
    float4 v = *(const float4*)(W + i);
    ushort4 o;
    o.x = f2bf(v.x); o.y = f2bf(v.y); o.z = f2bf(v.z); o.w = f2bf(v.w);
    *(ushort4*)(D + i) = o;
  } else if (b < 11264) {
    int q = b - 10240;
    int kb = (q >> 5) * 32, nb = (q & 31) * 32;
    int tx = threadIdx.x & 31, ty = threadIdx.x >> 5;
    for (int r = ty; r < 32; r += 8)
      tile[r][tx] = W2[(long)(kb + r) * 1024 + nb + tx];
    __syncthreads();
    for (int r = ty; r < 32; r += 8)
      WvT[(long)(nb + r) * 1024 + kb + tx] = f2bf(tile[tx][r]);
  } else {
    long i = ((long)(b - 11264) * 256 + threadIdx.x) * 4;
    float4 zz = {0.f, 0.f, 0.f, 0.f};
    *(float4*)(rsum + i) = zz;
  }
}

extern "C" void kernel_launch(void* const* d_in, const int* in_sizes, int n_in,
                              void* d_out, int out_size, void* d_ws, size_t ws_size,
                              hipStream_t stream) {
  const float* x  = (const float*)d_in[0];
  const float* Wq = (const float*)d_in[1];
  const float* Wk = (const float*)d_in[2];
  const float* Wv = (const float*)d_in[3];
  float* out = (float*)d_out;

  // workspace layout (bf16 = unsigned short), ~120 MB
  unsigned short* Xb  = (unsigned short*)d_ws;            // [8192][1024]
  unsigned short* Wqb = Xb  + (long)8192 * 1024;          // [1024][1024] bf16 [in][out]
  unsigned short* Wkb = Wqb + (long)1024 * 1024;          // [1024][1024] bf16 [in][out]
  unsigned short* TVB = Wkb + (long)1024 * 1024;          // [2048][1024]: Mt ; WvT
  unsigned short* T   = TVB + (long)2048 * 1024;          // [8192][1024]
  unsigned short* Vt  = T   + (long)8192 * 1024;          // [4][1024][2048] (follows T!)
  unsigned short* E   = Vt  + (long)8192 * 1024;          // [4][2048][2048] bf16 exp(s)
  float* rsum         = (float*)(E + (long)4 * 2048 * 2048); // [4][2048] fp32

  prep<<<11272, 256, 0, stream>>>(x, Wq, Wk, Wv, Xb, Wqb, Wkb,
                                  TVB + (long)1024 * 1024, rsum);

  // Mt[j][i] = sum_o Wk[j][o] Wq[i][o] = M[i][j], M = Wq Wk^T (full-GPU grid)
  mt64<<<dim3(16, 16, 1), 256, 0, stream>>>(Wkb, Wqb, TVB);

  // fused TV: [8192x2048] = Xb * [Mt;WvT]^T; robust 2-barrier, unswizzled
  gemm_tv2<<<dim3(16, 64, 1), 256, 0, stream>>>(Xb, TVB, T);

  // E = exp(T * Xb^T / 32) masked lower-tri + row sums; 2-wave + XCD swizzle
  scores2wz<<<dim3(272, 1, 4), 128, 0, stream>>>(T, Xb, rsum, E, 0.03125f);

  // out = (E * Vt^T)/rsum; stripe pairs (15-p, p) + XCD swizzle
  gemm_bt<3><<<dim3(16, 8, 4), 256, 0, stream>>>(E, Vt, out, rsum, nullptr, 2048,
      (long)2048 * 2048, (long)1024 * 2048, (long)2048 * 1024, 1.f);
}